// Round 1
// baseline (2609.297 us; speedup 1.0000x reference)
//
#include <hip/hip_runtime.h>

typedef unsigned short ushort_t;
typedef __attribute__((ext_vector_type(8))) short short8;
typedef __attribute__((ext_vector_type(4))) float floatx4;

#define BSZ   512
#define UNITS 256
#define IMG   64
#define STEPS 10
#define GATES 1024
// folded ext layout per batch row: [x_hat 4096 | h_dec 256 | h_enc 256]
#define KENC  4608
#define ESPLIT 8    // enc: 144 kt = 8 chunks of 18
#define DSPLIT 4    // dec: 16 kt = 4 chunks of 4
#define NBLK  256   // persistent grid: one block per CU
#define TM 128
#define TN 128
#define BK 32

__device__ inline float b2f(ushort_t u) {
  union { float f; unsigned int i; } v; v.i = ((unsigned int)u) << 16; return v.f;
}
__device__ inline ushort_t f2b(float f) {
  unsigned int u = __float_as_uint(f);
  u += 0x7fffu + ((u >> 16) & 1u);          // round-to-nearest-even
  return (ushort_t)(u >> 16);
}
__device__ inline float sigm(float x) { return 1.f / (1.f + __expf(-x)); }

#define GLL(g, l) __builtin_amdgcn_global_load_lds(                      \
    (const __attribute__((address_space(1))) void*)(g),                  \
    (__attribute__((address_space(3))) void*)(l), 16, 0, 0)

// ---------------------------------------------------------------------------
// Device-scope grid barrier (sense-reversing counter). bar[0]=cnt, bar[1]=gen.
// Agent-scope release/acquire atomics force per-XCD L2 writeback/invalidate,
// so plain global stores before the barrier are visible after it on all XCDs.
// ---------------------------------------------------------------------------
__device__ inline void gridbar(unsigned* bar) {
  __syncthreads();
  if (threadIdx.x == 0) {
    __threadfence();
    unsigned* cnt = bar;
    unsigned* gen = bar + 1;
    unsigned g = __hip_atomic_load(gen, __ATOMIC_RELAXED, __HIP_MEMORY_SCOPE_AGENT);
    unsigned a = __hip_atomic_fetch_add(cnt, 1u, __ATOMIC_ACQ_REL, __HIP_MEMORY_SCOPE_AGENT);
    if (a == NBLK - 1) {
      __hip_atomic_store(cnt, 0u, __ATOMIC_RELAXED, __HIP_MEMORY_SCOPE_AGENT);
      __hip_atomic_store(gen, g + 1u, __ATOMIC_RELEASE, __HIP_MEMORY_SCOPE_AGENT);
    } else {
      while (__hip_atomic_load(gen, __ATOMIC_ACQUIRE, __HIP_MEMORY_SCOPE_AGENT) == g)
        __builtin_amdgcn_s_sleep(1);
    }
    __threadfence();
  }
  __syncthreads();
}

// ---------------------------------------------------------------------------
// Fold patch weights into per-pixel weights + transpose (hi only).
// ---------------------------------------------------------------------------
__global__ __launch_bounds__(256) void k_prep_pix(const float* __restrict__ ek,
                                                  ushort_t* __restrict__ ohi) {
  __shared__ float T[64][68];
  int t = threadIdx.x;
  int pix0 = blockIdx.x * 64, n0 = blockIdx.y * 64;
  int r = t >> 2, seg = t & 3;
  int pix = pix0 + r;
  int ri = pix >> 6, ci = pix & 63;
  float4 acc4[4];
#pragma unroll
  for (int j = 0; j < 4; ++j) acc4[j] = float4{0.f, 0.f, 0.f, 0.f};
#pragma unroll
  for (int di = 0; di < 3; ++di) {
    int ii = ri - di;
    if (ii < 0 || (ii & 1)) continue;
    int oi = ii >> 1;  if (oi >= 32) continue;
#pragma unroll
    for (int dj = 0; dj < 3; ++dj) {
      int jj = ci - dj;
      if (jj < 0 || (jj & 1)) continue;
      int oj = jj >> 1;  if (oj >= 32) continue;
      const float* row = ek + (size_t)((oi * 32 + oj) * 9 + di * 3 + dj) * GATES
                         + n0 + seg * 16;
#pragma unroll
      for (int j = 0; j < 4; ++j) {
        float4 v = *(const float4*)(row + j * 4);
        acc4[j].x += v.x; acc4[j].y += v.y; acc4[j].z += v.z; acc4[j].w += v.w;
      }
    }
  }
#pragma unroll
  for (int j = 0; j < 4; ++j) *(float4*)&T[r][seg * 16 + j * 4] = acc4[j];
  __syncthreads();
  ushort_t thi[16];
#pragma unroll
  for (int j = 0; j < 16; ++j) thi[j] = f2b(T[seg * 16 + j][r]);
  size_t off = (size_t)(n0 + r) * KENC + pix0 + seg * 16;
  *(uint4*)(ohi + off)     = *(const uint4*)&thi[0];
  *(uint4*)(ohi + off + 8) = *(const uint4*)&thi[8];
}

// ---------------------------------------------------------------------------
// Multi-job transpose prep (one dispatch). Also zeroes the grid-barrier words.
// ---------------------------------------------------------------------------
__global__ __launch_bounds__(256) void k_prep_multi(
    const float* __restrict__ ek, const float* __restrict__ er,
    const float* __restrict__ dk, const float* __restrict__ dr,
    const float* __restrict__ Wdec,
    ushort_t* __restrict__ Wet_hi,
    ushort_t* __restrict__ Wdt_hi, ushort_t* __restrict__ Wdt_lo,
    ushort_t* __restrict__ Wct_hi, ushort_t* __restrict__ Wct_lo,
    unsigned* __restrict__ bar) {
  __shared__ float T[64][68];
  int t = threadIdx.x;
  int z = blockIdx.z;
  int k0 = blockIdx.x * 64, n0 = blockIdx.y * 64;
  int r = t >> 2, seg = t & 3;
  if (z == 0 && blockIdx.x == 0 && blockIdx.y == 0 && t == 0) {
    bar[0] = 0u; bar[1] = 0u;
  }

  const float *s0, *s1 = nullptr;
  ushort_t *ohi, *olo = nullptr;
  int src_ld, out_ld, koff;
  if (z == 0) { s0 = ek + (size_t)9216 * GATES; s1 = ek + (size_t)9472 * GATES;
                src_ld = GATES; ohi = Wet_hi; out_ld = KENC; koff = 4096; }
  else if (z == 1) { s0 = er; src_ld = GATES; ohi = Wet_hi; out_ld = KENC; koff = 4352; }
  else if (z == 2) { s0 = dk; src_ld = GATES; ohi = Wdt_hi; olo = Wdt_lo; out_ld = 512; koff = 0; }
  else if (z == 3) { s0 = dr; src_ld = GATES; ohi = Wdt_hi; olo = Wdt_lo; out_ld = 512; koff = 256; }
  else { s0 = Wdec; src_ld = 4096; ohi = Wct_hi; olo = Wct_lo; out_ld = 256; koff = 0;
         n0 += (z - 4) * 1024; }

  const float* src = s0 + (size_t)(k0 + r) * src_ld + n0 + seg * 16;
  const float* src2 = s1 ? (s1 + (size_t)(k0 + r) * src_ld + n0 + seg * 16) : nullptr;
#pragma unroll
  for (int j = 0; j < 4; ++j) {
    float4 v = *(const float4*)(src + j * 4);
    if (src2) {
      float4 w = *(const float4*)(src2 + j * 4);
      v.x += w.x; v.y += w.y; v.z += w.z; v.w += w.w;
    }
    *(float4*)&T[r][seg * 16 + j * 4] = v;
  }
  __syncthreads();
  ushort_t thi[16], tlo[16];
#pragma unroll
  for (int j = 0; j < 16; ++j) {
    float v = T[seg * 16 + j][r];
    ushort_t h = f2b(v);
    thi[j] = h;
    tlo[j] = f2b(v - b2f(h));
  }
  size_t off = (size_t)(n0 + r) * out_ld + koff + k0 + seg * 16;
  *(uint4*)(ohi + off)     = *(const uint4*)&thi[0];
  *(uint4*)(ohi + off + 8) = *(const uint4*)&thi[8];
  if (olo) {
    *(uint4*)(olo + off)     = *(const uint4*)&tlo[0];
    *(uint4*)(olo + off + 8) = *(const uint4*)&tlo[8];
  }
}

// ---------------------------------------------------------------------------
// Persistent kernel: all 10 steps, 5 phases/step, grid barriers in between.
// 256 blocks x 512 threads (8 waves) = 1 block/CU. LDS union = 48 KiB.
// ---------------------------------------------------------------------------
__global__ __launch_bounds__(512, 2) void k_persist(
    const float* __restrict__ x,
    const float* __restrict__ ebias, const float* __restrict__ dbias,
    const float* __restrict__ Wenc, const float* __restrict__ benc,
    const float* __restrict__ bdec,
    float* __restrict__ canvas, float* __restrict__ c_enc, float* __restrict__ c_dec,
    float* __restrict__ zep, float* __restrict__ zdp,
    ushort_t* __restrict__ ehi, ushort_t* __restrict__ dhi, ushort_t* __restrict__ dlo,
    const ushort_t* __restrict__ Wet_hi,
    const ushort_t* __restrict__ Wdt_hi, const ushort_t* __restrict__ Wdt_lo,
    const ushort_t* __restrict__ Wct_hi, const ushort_t* __restrict__ Wct_lo,
    unsigned* bar) {
  __shared__ __align__(16) ushort_t smem[24576];   // 48 KiB union for all phases
  const int b = blockIdx.x, t = threadIdx.x;
  const int lane = t & 63, w = t >> 6;
  const int q = lane >> 4, c16 = lane & 15;
  const int half = t >> 8, u8 = t & 255;
  const int rrow = b * 2 + half;                   // 2 batch rows per block

  // ---------------- preamble: zero state + step-0 x_hat (sigmoid(0)=0.5) ----
  {
    float4* cv4 = (float4*)canvas;
    float4 z4 = float4{0.f, 0.f, 0.f, 0.f};
#pragma unroll
    for (int i = 0; i < 4; ++i) cv4[b * 2048 + i * 512 + t] = z4;
    c_enc[b * 512 + t] = 0.f;
    c_dec[b * 512 + t] = 0.f;
    ehi[(size_t)rrow * KENC + 4096 + u8] = 0;
    ehi[(size_t)rrow * KENC + 4352 + u8] = 0;
    dhi[(size_t)rrow * 512 + u8] = 0; dhi[(size_t)rrow * 512 + 256 + u8] = 0;
    dlo[(size_t)rrow * 512 + u8] = 0; dlo[(size_t)rrow * 512 + 256 + u8] = 0;
    for (int pix = u8; pix < 4096; pix += 256)
      ehi[(size_t)rrow * KENC + pix] = f2b(x[(size_t)rrow * 4096 + pix] - 0.5f);
  }
  gridbar(bar);

  for (int s = 0; s < STEPS; ++s) {
    // ============ phase E: enc GEMM, pure bf16, 128x128 tile, split-K 8 =====
    {
      const int z = b >> 5, by = (b >> 3) & 3, bx = b & 7;
      const int m0 = by * TM, n0 = bx * TN, kstart = z * 18 * BK;
      const int wm = w >> 1, wn = w & 1;           // 4x2 waves -> 32m x 64n
      const ushort_t* pAh = ehi + (size_t)(m0 + (t >> 2)) * KENC + kstart + (t & 3) * 8;
      const ushort_t* pBh = Wet_hi + (size_t)(n0 + (t >> 2)) * KENC + kstart + (t & 3) * 8;
      const int d0 = t * 8;

      floatx4 acc[2][4];
#pragma unroll
      for (int i = 0; i < 2; ++i)
#pragma unroll
        for (int j = 0; j < 4; ++j) acc[i][j] = floatx4{0.f, 0.f, 0.f, 0.f};

      GLL(pAh, &smem[d0]); GLL(pBh, &smem[4096 + d0]);
      pAh += BK; pBh += BK;
      __syncthreads();
      for (int kt = 0; kt < 18; ++kt) {
        const int cur = (kt & 1) * 8192, nxt = 8192 - cur;
        if (kt + 1 < 18) {
          GLL(pAh, &smem[nxt + d0]); GLL(pBh, &smem[nxt + 4096 + d0]);
          pAh += BK; pBh += BK;
        }
        short8 ah[2], bh[4];
#pragma unroll
        for (int i = 0; i < 2; ++i)
          ah[i] = *(const short8*)&smem[cur + (wm * 32 + i * 16 + c16) * BK + q * 8];
#pragma unroll
        for (int j = 0; j < 4; ++j)
          bh[j] = *(const short8*)&smem[cur + 4096 + (wn * 64 + j * 16 + c16) * BK + q * 8];
#pragma unroll
        for (int mi = 0; mi < 2; ++mi)
#pragma unroll
          for (int ni = 0; ni < 4; ++ni)
            acc[mi][ni] = __builtin_amdgcn_mfma_f32_16x16x32_bf16(ah[mi], bh[ni], acc[mi][ni], 0, 0, 0);
        __syncthreads();
      }
      float* Cz = zep + (size_t)z * BSZ * GATES;
#pragma unroll
      for (int mi = 0; mi < 2; ++mi)
#pragma unroll
        for (int ni = 0; ni < 4; ++ni) {
          const int n = n0 + wn * 64 + ni * 16 + c16;
          const int mb = m0 + wm * 32 + mi * 16 + q * 4;
#pragma unroll
          for (int r = 0; r < 4; ++r)
            Cz[(size_t)(mb + r) * GATES + n] = acc[mi][ni][r];
        }
    }
    gridbar(bar);

    // ============ phase E2: enc LSTM + attention softmax + glimpse ==========
    {
      float* shf = (float*)smem;          // [0,512): h (2 rows); [512,532): logits
      float zi = ebias[u8], zf = ebias[u8 + 256];
      float zg = ebias[u8 + 512], zo = ebias[u8 + 768];
      for (int sp = 0; sp < ESPLIT; ++sp) {
        const float* zz = zep + ((size_t)sp * BSZ + rrow) * GATES;
        zi += zz[u8]; zf += zz[u8 + 256]; zg += zz[u8 + 512]; zo += zz[u8 + 768];
      }
      float c = c_enc[rrow * UNITS + u8];
      float cn = sigm(zf) * c + sigm(zi) * tanhf(zg);
      float h = sigm(zo) * tanhf(cn);
      c_enc[rrow * UNITS + u8] = cn;
      ehi[(size_t)rrow * KENC + 4352 + u8] = f2b(h);
      shf[half * 256 + u8] = h;
      __syncthreads();
      if (u8 < 64) {    // waves 0 and 4: full-wave shuffle reduce per row
        float acc[10];
#pragma unroll
        for (int j = 0; j < 10; ++j) acc[j] = 0.f;
        for (int qq = 0; qq < 4; ++qq) {
          float hv = shf[half * 256 + u8 + qq * 64];
          const float* wr = Wenc + (u8 + qq * 64) * 10;
#pragma unroll
          for (int j = 0; j < 10; ++j) acc[j] += hv * wr[j];
        }
        for (int off = 32; off > 0; off >>= 1)
#pragma unroll
          for (int j = 0; j < 10; ++j) acc[j] += __shfl_down(acc[j], off);
        if (u8 == 0)
          for (int j = 0; j < 10; ++j) shf[512 + half * 10 + j] = acc[j] + benc[j];
      }
      __syncthreads();
      float mx = shf[512 + half * 10];
      for (int j = 1; j < 10; ++j) mx = fmaxf(mx, shf[512 + half * 10 + j]);
      float e[10], se = 0.f;
      for (int j = 0; j < 10; ++j) { e[j] = __expf(shf[512 + half * 10 + j] - mx); se += e[j]; }
      float inv = 1.f / se;
      const float* wr = Wenc + u8 * 10;
      float zzv = 0.f;
      for (int j = 0; j < 10; ++j) zzv += e[j] * inv * wr[j];
      ushort_t zh = f2b(zzv);
      dhi[(size_t)rrow * 512 + u8] = zh;
      dlo[(size_t)rrow * 512 + u8] = f2b(zzv - b2f(zh));
    }
    gridbar(bar);

    // ============ phase D: dec GEMM, 3-product, 128x64 tile, split-K 4 ======
    {
      const int z = b >> 6, rem = b & 63, by = rem >> 4, bx = rem & 15;
      const int m0 = by * TM, n0 = bx * 64, kstart = z * 4 * BK;
      const int wm = w >> 1, wn = w & 1;           // 4x2 waves -> 32m x 32n
      const int ta = t & 255;
      const ushort_t* pAh = dhi + (size_t)(m0 + (t >> 2)) * 512 + kstart + (t & 3) * 8;
      const ushort_t* pAl = dlo + (size_t)(m0 + (t >> 2)) * 512 + kstart + (t & 3) * 8;
      const ushort_t* pB = ((t < 256) ? Wdt_hi : Wdt_lo)
                           + (size_t)(n0 + (ta >> 2)) * 512 + kstart + (ta & 3) * 8;
      const int dAh = t * 8, dAl = 4096 + t * 8;
      const int dB = ((t < 256) ? 8192 : 10240) + ta * 8;

      floatx4 acc[2][2];
#pragma unroll
      for (int i = 0; i < 2; ++i)
#pragma unroll
        for (int j = 0; j < 2; ++j) acc[i][j] = floatx4{0.f, 0.f, 0.f, 0.f};

      GLL(pAh, &smem[dAh]); GLL(pAl, &smem[dAl]); GLL(pB, &smem[dB]);
      pAh += BK; pAl += BK; pB += BK;
      __syncthreads();
      for (int kt = 0; kt < 4; ++kt) {
        const int cur = (kt & 1) * 12288, nxt = 12288 - cur;
        if (kt + 1 < 4) {
          GLL(pAh, &smem[nxt + dAh]); GLL(pAl, &smem[nxt + dAl]); GLL(pB, &smem[nxt + dB]);
          pAh += BK; pAl += BK; pB += BK;
        }
        short8 ah[2], al[2], bh[2], bl[2];
#pragma unroll
        for (int i = 0; i < 2; ++i) {
          const int ra = (wm * 32 + i * 16 + c16) * BK + q * 8;
          ah[i] = *(const short8*)&smem[cur + ra];
          al[i] = *(const short8*)&smem[cur + 4096 + ra];
          const int rb = (wn * 32 + i * 16 + c16) * BK + q * 8;
          bh[i] = *(const short8*)&smem[cur + 8192 + rb];
          bl[i] = *(const short8*)&smem[cur + 10240 + rb];
        }
#pragma unroll
        for (int mi = 0; mi < 2; ++mi)
#pragma unroll
          for (int ni = 0; ni < 2; ++ni) {
            acc[mi][ni] = __builtin_amdgcn_mfma_f32_16x16x32_bf16(ah[mi], bh[ni], acc[mi][ni], 0, 0, 0);
            acc[mi][ni] = __builtin_amdgcn_mfma_f32_16x16x32_bf16(ah[mi], bl[ni], acc[mi][ni], 0, 0, 0);
            acc[mi][ni] = __builtin_amdgcn_mfma_f32_16x16x32_bf16(al[mi], bh[ni], acc[mi][ni], 0, 0, 0);
          }
        __syncthreads();
      }
      float* Cz = zdp + (size_t)z * BSZ * GATES;
#pragma unroll
      for (int mi = 0; mi < 2; ++mi)
#pragma unroll
        for (int ni = 0; ni < 2; ++ni) {
          const int n = n0 + wn * 32 + ni * 16 + c16;
          const int mb = m0 + wm * 32 + mi * 16 + q * 4;
#pragma unroll
          for (int r = 0; r < 4; ++r)
            Cz[(size_t)(mb + r) * GATES + n] = acc[mi][ni][r];
        }
    }
    gridbar(bar);

    // ============ phase D2: dec LSTM ========================================
    {
      float zi = dbias[u8], zf = dbias[u8 + 256];
      float zg = dbias[u8 + 512], zo = dbias[u8 + 768];
      for (int sp = 0; sp < DSPLIT; ++sp) {
        const float* zz = zdp + ((size_t)sp * BSZ + rrow) * GATES;
        zi += zz[u8]; zf += zz[u8 + 256]; zg += zz[u8 + 512]; zo += zz[u8 + 768];
      }
      float c = c_dec[rrow * UNITS + u8];
      float cn = sigm(zf) * c + sigm(zi) * tanhf(zg);
      float h = sigm(zo) * tanhf(cn);
      c_dec[rrow * UNITS + u8] = cn;
      ushort_t hh = f2b(h);
      dhi[(size_t)rrow * 512 + 256 + u8] = hh;
      dlo[(size_t)rrow * 512 + 256 + u8] = f2b(h - b2f(hh));
      ehi[(size_t)rrow * KENC + 4096 + u8] = hh;
    }
    gridbar(bar);

    // ============ phase C: canvas GEMM + fused x_hat, 64x128 tiles ==========
    {
      const int by = b >> 5, bx = b & 31;          // 8 m-tiles x 32 n-tiles
      const int m0 = by * 64, n0 = bx * TN;
      const int wm = w >> 2, wn = w & 3;           // 2x4 waves -> 32m x 32n
      const int ia = t & 255;
      const ushort_t* pA = ((t < 256) ? (dhi + 256) : (dlo + 256))
                           + (size_t)(m0 + (ia >> 2)) * 512 + (ia & 3) * 8;
      const ushort_t* pBh = Wct_hi + (size_t)(n0 + (t >> 2)) * 256 + (t & 3) * 8;
      const ushort_t* pBl = Wct_lo + (size_t)(n0 + (t >> 2)) * 256 + (t & 3) * 8;
      const int dA = ((t < 256) ? 0 : 2048) + ia * 8;
      const int dBh = 4096 + t * 8, dBl = 8192 + t * 8;

      floatx4 acc[2][2];
#pragma unroll
      for (int i = 0; i < 2; ++i)
#pragma unroll
        for (int j = 0; j < 2; ++j) acc[i][j] = floatx4{0.f, 0.f, 0.f, 0.f};

      GLL(pA, &smem[dA]); GLL(pBh, &smem[dBh]); GLL(pBl, &smem[dBl]);
      pA += BK; pBh += BK; pBl += BK;
      __syncthreads();
      for (int kt = 0; kt < 8; ++kt) {
        const int cur = (kt & 1) * 12288, nxt = 12288 - cur;
        if (kt + 1 < 8) {
          GLL(pA, &smem[nxt + dA]); GLL(pBh, &smem[nxt + dBh]); GLL(pBl, &smem[nxt + dBl]);
          pA += BK; pBh += BK; pBl += BK;
        }
        short8 ah[2], al[2], bh[2], bl[2];
#pragma unroll
        for (int i = 0; i < 2; ++i) {
          const int ra = (wm * 32 + i * 16 + c16) * BK + q * 8;
          ah[i] = *(const short8*)&smem[cur + ra];
          al[i] = *(const short8*)&smem[cur + 2048 + ra];
          const int rb = (wn * 32 + i * 16 + c16) * BK + q * 8;
          bh[i] = *(const short8*)&smem[cur + 4096 + rb];
          bl[i] = *(const short8*)&smem[cur + 8192 + rb];
        }
#pragma unroll
        for (int mi = 0; mi < 2; ++mi)
#pragma unroll
          for (int ni = 0; ni < 2; ++ni) {
            acc[mi][ni] = __builtin_amdgcn_mfma_f32_16x16x32_bf16(ah[mi], bh[ni], acc[mi][ni], 0, 0, 0);
            acc[mi][ni] = __builtin_amdgcn_mfma_f32_16x16x32_bf16(ah[mi], bl[ni], acc[mi][ni], 0, 0, 0);
            acc[mi][ni] = __builtin_amdgcn_mfma_f32_16x16x32_bf16(al[mi], bh[ni], acc[mi][ni], 0, 0, 0);
          }
        __syncthreads();
      }
#pragma unroll
      for (int mi = 0; mi < 2; ++mi)
#pragma unroll
        for (int ni = 0; ni < 2; ++ni) {
          const int n = n0 + wn * 32 + ni * 16 + c16;
          const int mb = m0 + wm * 32 + mi * 16 + q * 4;
          const float bv = bdec[n];
#pragma unroll
          for (int r = 0; r < 4; ++r) {
            const int m = mb + r;
            const size_t idx = (size_t)m * 4096 + n;
            const float cv = canvas[idx] + acc[mi][ni][r] + bv;
            canvas[idx] = cv;
            ehi[(size_t)m * KENC + n] = f2b(x[idx] - sigm(cv));
          }
        }
    }
    if (s + 1 < STEPS) gridbar(bar);
  }
}

// ---------------------------------------------------------------------------
extern "C" void kernel_launch(void* const* d_in, const int* in_sizes, int n_in,
                              void* d_out, int out_size, void* d_ws, size_t ws_size,
                              hipStream_t stream) {
  const float* x     = (const float*)d_in[0];
  const float* ek    = (const float*)d_in[1];   // [9728,1024]
  const float* er    = (const float*)d_in[2];   // [256,1024]
  const float* ebias = (const float*)d_in[3];
  const float* dk    = (const float*)d_in[4];   // [256,1024]
  const float* dr    = (const float*)d_in[5];   // [256,1024]
  const float* dbias = (const float*)d_in[6];
  const float* Wenc  = (const float*)d_in[7];   // [256,10]
  const float* benc  = (const float*)d_in[8];
  const float* Wdec  = (const float*)d_in[9];   // [256,4096]
  const float* bdec  = (const float*)d_in[10];

  float* canvas = (float*)d_out;                // [512, 4096] — persistent canvas

  char* p = (char*)d_ws;
  float* c_enc  = (float*)p;        p += (size_t)BSZ * UNITS * 4;
  float* c_dec  = (float*)p;        p += (size_t)BSZ * UNITS * 4;
  float* zep    = (float*)p;        p += (size_t)ESPLIT * BSZ * GATES * 4;
  float* zdp    = (float*)p;        p += (size_t)DSPLIT * BSZ * GATES * 4;
  ushort_t* ehi = (ushort_t*)p;     p += (size_t)BSZ * KENC * 2;
  ushort_t* dhi = (ushort_t*)p;     p += (size_t)BSZ * 512 * 2;
  ushort_t* dlo = (ushort_t*)p;     p += (size_t)BSZ * 512 * 2;
  ushort_t* Wet_hi = (ushort_t*)p;  p += (size_t)GATES * KENC * 2;      // [1024][4608]
  ushort_t* Wdt_hi = (ushort_t*)p;  p += (size_t)GATES * 512 * 2;       // [1024][512]
  ushort_t* Wdt_lo = (ushort_t*)p;  p += (size_t)GATES * 512 * 2;
  ushort_t* Wct_hi = (ushort_t*)p;  p += (size_t)4096 * UNITS * 2;      // [4096][256]
  ushort_t* Wct_lo = (ushort_t*)p;  p += (size_t)4096 * UNITS * 2;
  unsigned* bar = (unsigned*)p;     p += 8;

  // ---- weight prep (once per launch) ----
  k_prep_pix<<<dim3(64, 16), 256, 0, stream>>>(ek, Wet_hi);
  k_prep_multi<<<dim3(4, 16, 8), 256, 0, stream>>>(ek, er, dk, dr, Wdec,
                                                   Wet_hi, Wdt_hi, Wdt_lo,
                                                   Wct_hi, Wct_lo, bar);

  // ---- persistent 10-step kernel (cooperative; fallback to plain launch) ----
  void* args[] = {(void*)&x, (void*)&ebias, (void*)&dbias, (void*)&Wenc,
                  (void*)&benc, (void*)&bdec, (void*)&canvas, (void*)&c_enc,
                  (void*)&c_dec, (void*)&zep, (void*)&zdp, (void*)&ehi,
                  (void*)&dhi, (void*)&dlo, (void*)&Wet_hi, (void*)&Wdt_hi,
                  (void*)&Wdt_lo, (void*)&Wct_hi, (void*)&Wct_lo, (void*)&bar};
  if (hipLaunchCooperativeKernel((void*)k_persist, dim3(NBLK), dim3(512),
                                 args, 0, stream) != hipSuccess) {
    k_persist<<<dim3(NBLK), dim3(512), 0, stream>>>(
        x, ebias, dbias, Wenc, benc, bdec, canvas, c_enc, c_dec, zep, zdp,
        ehi, dhi, dlo, Wet_hi, Wdt_hi, Wdt_lo, Wct_hi, Wct_lo, bar);
  }
}

// Round 2
// 1841.555 us; speedup vs baseline: 1.4169x; 1.4169x over previous
//
#include <hip/hip_runtime.h>

typedef unsigned short ushort_t;
typedef __attribute__((ext_vector_type(8))) short short8;
typedef __attribute__((ext_vector_type(4))) float floatx4;

#define BSZ   512
#define UNITS 256
#define IMG   64
#define STEPS 10
#define GATES 1024
// folded ext layout per batch row: [x_hat 4096 | h_dec 256 | h_enc 256]
#define KENC  4608
#define ESPLIT 8    // enc: 144 kt = 8 chunks of 18
#define DSPLIT 4    // dec: 16 kt = 4 chunks of 4
#define NBLK  256   // persistent grid: one block per CU
#define TM 128
#define TN 128
#define BK 32
#define FLAG_STRIDE 32                       // 128 B per block flag slot

__device__ inline float b2f(ushort_t u) {
  union { float f; unsigned int i; } v; v.i = ((unsigned int)u) << 16; return v.f;
}
__device__ inline ushort_t f2b(float f) {
  unsigned int u = __float_as_uint(f);
  u += 0x7fffu + ((u >> 16) & 1u);          // round-to-nearest-even
  return (ushort_t)(u >> 16);
}
__device__ inline float sigm(float x) { return 1.f / (1.f + __expf(-x)); }

#define GLL(g, l) __builtin_amdgcn_global_load_lds(                      \
    (const __attribute__((address_space(1))) void*)(g),                  \
    (__attribute__((address_space(3))) void*)(l), 16, 0, 0)

// ---------------------------------------------------------------------------
// Grid barrier, contention-free: per-block arrival flags (128B-strided,
// release-stored) + leader block aggregating with RELAXED polls + one
// generation word. Waiters spin with RELAXED loads (no per-iteration cache
// invalidate) and run a single agent-scope acquire fence on exit.
// bar layout: [NBLK*FLAG_STRIDE flags][gen]
// ---------------------------------------------------------------------------
__device__ inline void gridbar(unsigned* bar, unsigned id) {
  __syncthreads();
  const int b = blockIdx.x, t = threadIdx.x;
  unsigned* gen = bar + NBLK * FLAG_STRIDE;
  if (b == 0) {
    if (t > 0 && t < NBLK) {
      while (__hip_atomic_load(bar + t * FLAG_STRIDE, __ATOMIC_RELAXED,
                               __HIP_MEMORY_SCOPE_AGENT) < id)
        __builtin_amdgcn_s_sleep(2);
    }
    __syncthreads();
    if (t == 0)
      __hip_atomic_store(gen, id, __ATOMIC_RELEASE, __HIP_MEMORY_SCOPE_AGENT);
  } else {
    if (t == 0) {
      __hip_atomic_store(bar + b * FLAG_STRIDE, id, __ATOMIC_RELEASE,
                         __HIP_MEMORY_SCOPE_AGENT);
      while (__hip_atomic_load(gen, __ATOMIC_RELAXED,
                               __HIP_MEMORY_SCOPE_AGENT) < id)
        __builtin_amdgcn_s_sleep(4);
    }
  }
  __builtin_amdgcn_fence(__ATOMIC_ACQUIRE, "agent");
  __syncthreads();
}

// ---------------------------------------------------------------------------
// Fold patch weights into per-pixel weights + transpose (hi only).
// ---------------------------------------------------------------------------
__global__ __launch_bounds__(256) void k_prep_pix(const float* __restrict__ ek,
                                                  ushort_t* __restrict__ ohi) {
  __shared__ float T[64][68];
  int t = threadIdx.x;
  int pix0 = blockIdx.x * 64, n0 = blockIdx.y * 64;
  int r = t >> 2, seg = t & 3;
  int pix = pix0 + r;
  int ri = pix >> 6, ci = pix & 63;
  float4 acc4[4];
#pragma unroll
  for (int j = 0; j < 4; ++j) acc4[j] = float4{0.f, 0.f, 0.f, 0.f};
#pragma unroll
  for (int di = 0; di < 3; ++di) {
    int ii = ri - di;
    if (ii < 0 || (ii & 1)) continue;
    int oi = ii >> 1;  if (oi >= 32) continue;
#pragma unroll
    for (int dj = 0; dj < 3; ++dj) {
      int jj = ci - dj;
      if (jj < 0 || (jj & 1)) continue;
      int oj = jj >> 1;  if (oj >= 32) continue;
      const float* row = ek + (size_t)((oi * 32 + oj) * 9 + di * 3 + dj) * GATES
                         + n0 + seg * 16;
#pragma unroll
      for (int j = 0; j < 4; ++j) {
        float4 v = *(const float4*)(row + j * 4);
        acc4[j].x += v.x; acc4[j].y += v.y; acc4[j].z += v.z; acc4[j].w += v.w;
      }
    }
  }
#pragma unroll
  for (int j = 0; j < 4; ++j) *(float4*)&T[r][seg * 16 + j * 4] = acc4[j];
  __syncthreads();
  ushort_t thi[16];
#pragma unroll
  for (int j = 0; j < 16; ++j) thi[j] = f2b(T[seg * 16 + j][r]);
  size_t off = (size_t)(n0 + r) * KENC + pix0 + seg * 16;
  *(uint4*)(ohi + off)     = *(const uint4*)&thi[0];
  *(uint4*)(ohi + off + 8) = *(const uint4*)&thi[8];
}

// ---------------------------------------------------------------------------
// Multi-job transpose prep (one dispatch). Also zeroes the grid-barrier words.
// ---------------------------------------------------------------------------
__global__ __launch_bounds__(256) void k_prep_multi(
    const float* __restrict__ ek, const float* __restrict__ er,
    const float* __restrict__ dk, const float* __restrict__ dr,
    const float* __restrict__ Wdec,
    ushort_t* __restrict__ Wet_hi,
    ushort_t* __restrict__ Wdt_hi, ushort_t* __restrict__ Wdt_lo,
    ushort_t* __restrict__ Wct_hi, ushort_t* __restrict__ Wct_lo,
    unsigned* __restrict__ bar) {
  __shared__ float T[64][68];
  int t = threadIdx.x;
  int z = blockIdx.z;
  int k0 = blockIdx.x * 64, n0 = blockIdx.y * 64;
  int r = t >> 2, seg = t & 3;
  if (z == 0) {
    int fid = (blockIdx.y * 4 + blockIdx.x) * 256 + t;
    if (fid <= NBLK * FLAG_STRIDE) bar[fid] = 0u;   // flags + gen
  }

  const float *s0, *s1 = nullptr;
  ushort_t *ohi, *olo = nullptr;
  int src_ld, out_ld, koff;
  if (z == 0) { s0 = ek + (size_t)9216 * GATES; s1 = ek + (size_t)9472 * GATES;
                src_ld = GATES; ohi = Wet_hi; out_ld = KENC; koff = 4096; }
  else if (z == 1) { s0 = er; src_ld = GATES; ohi = Wet_hi; out_ld = KENC; koff = 4352; }
  else if (z == 2) { s0 = dk; src_ld = GATES; ohi = Wdt_hi; olo = Wdt_lo; out_ld = 512; koff = 0; }
  else if (z == 3) { s0 = dr; src_ld = GATES; ohi = Wdt_hi; olo = Wdt_lo; out_ld = 512; koff = 256; }
  else { s0 = Wdec; src_ld = 4096; ohi = Wct_hi; olo = Wct_lo; out_ld = 256; koff = 0;
         n0 += (z - 4) * 1024; }

  const float* src = s0 + (size_t)(k0 + r) * src_ld + n0 + seg * 16;
  const float* src2 = s1 ? (s1 + (size_t)(k0 + r) * src_ld + n0 + seg * 16) : nullptr;
#pragma unroll
  for (int j = 0; j < 4; ++j) {
    float4 v = *(const float4*)(src + j * 4);
    if (src2) {
      float4 w = *(const float4*)(src2 + j * 4);
      v.x += w.x; v.y += w.y; v.z += w.z; v.w += w.w;
    }
    *(float4*)&T[r][seg * 16 + j * 4] = v;
  }
  __syncthreads();
  ushort_t thi[16], tlo[16];
#pragma unroll
  for (int j = 0; j < 16; ++j) {
    float v = T[seg * 16 + j][r];
    ushort_t h = f2b(v);
    thi[j] = h;
    tlo[j] = f2b(v - b2f(h));
  }
  size_t off = (size_t)(n0 + r) * out_ld + koff + k0 + seg * 16;
  *(uint4*)(ohi + off)     = *(const uint4*)&thi[0];
  *(uint4*)(ohi + off + 8) = *(const uint4*)&thi[8];
  if (olo) {
    *(uint4*)(olo + off)     = *(const uint4*)&tlo[0];
    *(uint4*)(olo + off + 8) = *(const uint4*)&tlo[8];
  }
}

// ---------------------------------------------------------------------------
// Persistent kernel: all 10 steps, 5 phases/step, grid barriers in between.
// 256 blocks x 512 threads (8 waves) = 1 block/CU. LDS union = 48 KiB.
// ---------------------------------------------------------------------------
__global__ __launch_bounds__(512, 2) void k_persist(
    const float* __restrict__ x,
    const float* __restrict__ ebias, const float* __restrict__ dbias,
    const float* __restrict__ Wenc, const float* __restrict__ benc,
    const float* __restrict__ bdec,
    float* __restrict__ canvas, float* __restrict__ c_enc, float* __restrict__ c_dec,
    float* __restrict__ zep, float* __restrict__ zdp,
    ushort_t* __restrict__ ehi, ushort_t* __restrict__ dhi, ushort_t* __restrict__ dlo,
    const ushort_t* __restrict__ Wet_hi,
    const ushort_t* __restrict__ Wdt_hi, const ushort_t* __restrict__ Wdt_lo,
    const ushort_t* __restrict__ Wct_hi, const ushort_t* __restrict__ Wct_lo,
    unsigned* bar) {
  __shared__ __align__(16) ushort_t smem[24576];   // 48 KiB union for all phases
  const int b = blockIdx.x, t = threadIdx.x;
  const int lane = t & 63, w = t >> 6;
  const int q = lane >> 4, c16 = lane & 15;
  const int half = t >> 8, u8 = t & 255;
  const int rrow = b * 2 + half;                   // 2 batch rows per block
  unsigned barid = 0;

  // ---------------- preamble: zero state + step-0 x_hat (sigmoid(0)=0.5) ----
  {
    float4* cv4 = (float4*)canvas;
    float4 z4 = float4{0.f, 0.f, 0.f, 0.f};
#pragma unroll
    for (int i = 0; i < 4; ++i) cv4[b * 2048 + i * 512 + t] = z4;
    c_enc[b * 512 + t] = 0.f;
    c_dec[b * 512 + t] = 0.f;
    ehi[(size_t)rrow * KENC + 4096 + u8] = 0;
    ehi[(size_t)rrow * KENC + 4352 + u8] = 0;
    dhi[(size_t)rrow * 512 + u8] = 0; dhi[(size_t)rrow * 512 + 256 + u8] = 0;
    dlo[(size_t)rrow * 512 + u8] = 0; dlo[(size_t)rrow * 512 + 256 + u8] = 0;
    for (int pix = u8; pix < 4096; pix += 256)
      ehi[(size_t)rrow * KENC + pix] = f2b(x[(size_t)rrow * 4096 + pix] - 0.5f);
  }
  gridbar(bar, ++barid);

  for (int s = 0; s < STEPS; ++s) {
    // ============ phase E: enc GEMM, pure bf16, 128x128 tile, split-K 8 =====
    {
      const int z = b >> 5, by = (b >> 3) & 3, bx = b & 7;
      const int m0 = by * TM, n0 = bx * TN, kstart = z * 18 * BK;
      const int wm = w >> 1, wn = w & 1;           // 4x2 waves -> 32m x 64n
      const ushort_t* pAh = ehi + (size_t)(m0 + (t >> 2)) * KENC + kstart + (t & 3) * 8;
      const ushort_t* pBh = Wet_hi + (size_t)(n0 + (t >> 2)) * KENC + kstart + (t & 3) * 8;
      const int d0 = t * 8;

      floatx4 acc[2][4];
#pragma unroll
      for (int i = 0; i < 2; ++i)
#pragma unroll
        for (int j = 0; j < 4; ++j) acc[i][j] = floatx4{0.f, 0.f, 0.f, 0.f};

      GLL(pAh, &smem[d0]); GLL(pBh, &smem[4096 + d0]);
      pAh += BK; pBh += BK;
      __syncthreads();
      for (int kt = 0; kt < 18; ++kt) {
        const int cur = (kt & 1) * 8192, nxt = 8192 - cur;
        if (kt + 1 < 18) {
          GLL(pAh, &smem[nxt + d0]); GLL(pBh, &smem[nxt + 4096 + d0]);
          pAh += BK; pBh += BK;
        }
        short8 ah[2], bh[4];
#pragma unroll
        for (int i = 0; i < 2; ++i)
          ah[i] = *(const short8*)&smem[cur + (wm * 32 + i * 16 + c16) * BK + q * 8];
#pragma unroll
        for (int j = 0; j < 4; ++j)
          bh[j] = *(const short8*)&smem[cur + 4096 + (wn * 64 + j * 16 + c16) * BK + q * 8];
#pragma unroll
        for (int mi = 0; mi < 2; ++mi)
#pragma unroll
          for (int ni = 0; ni < 4; ++ni)
            acc[mi][ni] = __builtin_amdgcn_mfma_f32_16x16x32_bf16(ah[mi], bh[ni], acc[mi][ni], 0, 0, 0);
        __syncthreads();
      }
      float* Cz = zep + (size_t)z * BSZ * GATES;
#pragma unroll
      for (int mi = 0; mi < 2; ++mi)
#pragma unroll
        for (int ni = 0; ni < 4; ++ni) {
          const int n = n0 + wn * 64 + ni * 16 + c16;
          const int mb = m0 + wm * 32 + mi * 16 + q * 4;
#pragma unroll
          for (int r = 0; r < 4; ++r)
            Cz[(size_t)(mb + r) * GATES + n] = acc[mi][ni][r];
        }
    }
    gridbar(bar, ++barid);

    // ============ phase E2: enc LSTM + attention softmax + glimpse ==========
    {
      float* shf = (float*)smem;          // [0,512): h (2 rows); [512,532): logits
      float zi = ebias[u8], zf = ebias[u8 + 256];
      float zg = ebias[u8 + 512], zo = ebias[u8 + 768];
      for (int sp = 0; sp < ESPLIT; ++sp) {
        const float* zz = zep + ((size_t)sp * BSZ + rrow) * GATES;
        zi += zz[u8]; zf += zz[u8 + 256]; zg += zz[u8 + 512]; zo += zz[u8 + 768];
      }
      float c = c_enc[rrow * UNITS + u8];
      float cn = sigm(zf) * c + sigm(zi) * tanhf(zg);
      float h = sigm(zo) * tanhf(cn);
      c_enc[rrow * UNITS + u8] = cn;
      ehi[(size_t)rrow * KENC + 4352 + u8] = f2b(h);
      shf[half * 256 + u8] = h;
      __syncthreads();
      if (u8 < 64) {    // waves 0 and 4: full-wave shuffle reduce per row
        float acc[10];
#pragma unroll
        for (int j = 0; j < 10; ++j) acc[j] = 0.f;
        for (int qq = 0; qq < 4; ++qq) {
          float hv = shf[half * 256 + u8 + qq * 64];
          const float* wr = Wenc + (u8 + qq * 64) * 10;
#pragma unroll
          for (int j = 0; j < 10; ++j) acc[j] += hv * wr[j];
        }
        for (int off = 32; off > 0; off >>= 1)
#pragma unroll
          for (int j = 0; j < 10; ++j) acc[j] += __shfl_down(acc[j], off);
        if (u8 == 0)
          for (int j = 0; j < 10; ++j) shf[512 + half * 10 + j] = acc[j] + benc[j];
      }
      __syncthreads();
      float mx = shf[512 + half * 10];
      for (int j = 1; j < 10; ++j) mx = fmaxf(mx, shf[512 + half * 10 + j]);
      float e[10], se = 0.f;
      for (int j = 0; j < 10; ++j) { e[j] = __expf(shf[512 + half * 10 + j] - mx); se += e[j]; }
      float inv = 1.f / se;
      const float* wr = Wenc + u8 * 10;
      float zzv = 0.f;
      for (int j = 0; j < 10; ++j) zzv += e[j] * inv * wr[j];
      ushort_t zh = f2b(zzv);
      dhi[(size_t)rrow * 512 + u8] = zh;
      dlo[(size_t)rrow * 512 + u8] = f2b(zzv - b2f(zh));
    }
    gridbar(bar, ++barid);

    // ============ phase D: dec GEMM, 3-product, 128x64 tile, split-K 4 ======
    {
      const int z = b >> 6, rem = b & 63, by = rem >> 4, bx = rem & 15;
      const int m0 = by * TM, n0 = bx * 64, kstart = z * 4 * BK;
      const int wm = w >> 1, wn = w & 1;           // 4x2 waves -> 32m x 32n
      const int ta = t & 255;
      const ushort_t* pAh = dhi + (size_t)(m0 + (t >> 2)) * 512 + kstart + (t & 3) * 8;
      const ushort_t* pAl = dlo + (size_t)(m0 + (t >> 2)) * 512 + kstart + (t & 3) * 8;
      const ushort_t* pB = ((t < 256) ? Wdt_hi : Wdt_lo)
                           + (size_t)(n0 + (ta >> 2)) * 512 + kstart + (ta & 3) * 8;
      const int dAh = t * 8, dAl = 4096 + t * 8;
      const int dB = ((t < 256) ? 8192 : 10240) + ta * 8;

      floatx4 acc[2][2];
#pragma unroll
      for (int i = 0; i < 2; ++i)
#pragma unroll
        for (int j = 0; j < 2; ++j) acc[i][j] = floatx4{0.f, 0.f, 0.f, 0.f};

      GLL(pAh, &smem[dAh]); GLL(pAl, &smem[dAl]); GLL(pB, &smem[dB]);
      pAh += BK; pAl += BK; pB += BK;
      __syncthreads();
      for (int kt = 0; kt < 4; ++kt) {
        const int cur = (kt & 1) * 12288, nxt = 12288 - cur;
        if (kt + 1 < 4) {
          GLL(pAh, &smem[nxt + dAh]); GLL(pAl, &smem[nxt + dAl]); GLL(pB, &smem[nxt + dB]);
          pAh += BK; pAl += BK; pB += BK;
        }
        short8 ah[2], al[2], bh[2], bl[2];
#pragma unroll
        for (int i = 0; i < 2; ++i) {
          const int ra = (wm * 32 + i * 16 + c16) * BK + q * 8;
          ah[i] = *(const short8*)&smem[cur + ra];
          al[i] = *(const short8*)&smem[cur + 4096 + ra];
          const int rb = (wn * 32 + i * 16 + c16) * BK + q * 8;
          bh[i] = *(const short8*)&smem[cur + 8192 + rb];
          bl[i] = *(const short8*)&smem[cur + 10240 + rb];
        }
#pragma unroll
        for (int mi = 0; mi < 2; ++mi)
#pragma unroll
          for (int ni = 0; ni < 2; ++ni) {
            acc[mi][ni] = __builtin_amdgcn_mfma_f32_16x16x32_bf16(ah[mi], bh[ni], acc[mi][ni], 0, 0, 0);
            acc[mi][ni] = __builtin_amdgcn_mfma_f32_16x16x32_bf16(ah[mi], bl[ni], acc[mi][ni], 0, 0, 0);
            acc[mi][ni] = __builtin_amdgcn_mfma_f32_16x16x32_bf16(al[mi], bh[ni], acc[mi][ni], 0, 0, 0);
          }
        __syncthreads();
      }
      float* Cz = zdp + (size_t)z * BSZ * GATES;
#pragma unroll
      for (int mi = 0; mi < 2; ++mi)
#pragma unroll
        for (int ni = 0; ni < 2; ++ni) {
          const int n = n0 + wn * 32 + ni * 16 + c16;
          const int mb = m0 + wm * 32 + mi * 16 + q * 4;
#pragma unroll
          for (int r = 0; r < 4; ++r)
            Cz[(size_t)(mb + r) * GATES + n] = acc[mi][ni][r];
        }
    }
    gridbar(bar, ++barid);

    // ============ phase D2: dec LSTM ========================================
    {
      float zi = dbias[u8], zf = dbias[u8 + 256];
      float zg = dbias[u8 + 512], zo = dbias[u8 + 768];
      for (int sp = 0; sp < DSPLIT; ++sp) {
        const float* zz = zdp + ((size_t)sp * BSZ + rrow) * GATES;
        zi += zz[u8]; zf += zz[u8 + 256]; zg += zz[u8 + 512]; zo += zz[u8 + 768];
      }
      float c = c_dec[rrow * UNITS + u8];
      float cn = sigm(zf) * c + sigm(zi) * tanhf(zg);
      float h = sigm(zo) * tanhf(cn);
      c_dec[rrow * UNITS + u8] = cn;
      ushort_t hh = f2b(h);
      dhi[(size_t)rrow * 512 + 256 + u8] = hh;
      dlo[(size_t)rrow * 512 + 256 + u8] = f2b(h - b2f(hh));
      ehi[(size_t)rrow * KENC + 4096 + u8] = hh;
    }
    gridbar(bar, ++barid);

    // ============ phase C: canvas GEMM + fused x_hat, 64x128 tiles ==========
    {
      const int by = b >> 5, bx = b & 31;          // 8 m-tiles x 32 n-tiles
      const int m0 = by * 64, n0 = bx * TN;
      const int wm = w >> 2, wn = w & 3;           // 2x4 waves -> 32m x 32n
      const int ia = t & 255;
      const ushort_t* pA = ((t < 256) ? (dhi + 256) : (dlo + 256))
                           + (size_t)(m0 + (ia >> 2)) * 512 + (ia & 3) * 8;
      const ushort_t* pBh = Wct_hi + (size_t)(n0 + (t >> 2)) * 256 + (t & 3) * 8;
      const ushort_t* pBl = Wct_lo + (size_t)(n0 + (t >> 2)) * 256 + (t & 3) * 8;
      const int dA = ((t < 256) ? 0 : 2048) + ia * 8;
      const int dBh = 4096 + t * 8, dBl = 8192 + t * 8;

      floatx4 acc[2][2];
#pragma unroll
      for (int i = 0; i < 2; ++i)
#pragma unroll
        for (int j = 0; j < 2; ++j) acc[i][j] = floatx4{0.f, 0.f, 0.f, 0.f};

      GLL(pA, &smem[dA]); GLL(pBh, &smem[dBh]); GLL(pBl, &smem[dBl]);
      pA += BK; pBh += BK; pBl += BK;
      __syncthreads();
      for (int kt = 0; kt < 8; ++kt) {
        const int cur = (kt & 1) * 12288, nxt = 12288 - cur;
        if (kt + 1 < 8) {
          GLL(pA, &smem[nxt + dA]); GLL(pBh, &smem[nxt + dBh]); GLL(pBl, &smem[nxt + dBl]);
          pA += BK; pBh += BK; pBl += BK;
        }
        short8 ah[2], al[2], bh[2], bl[2];
#pragma unroll
        for (int i = 0; i < 2; ++i) {
          const int ra = (wm * 32 + i * 16 + c16) * BK + q * 8;
          ah[i] = *(const short8*)&smem[cur + ra];
          al[i] = *(const short8*)&smem[cur + 2048 + ra];
          const int rb = (wn * 32 + i * 16 + c16) * BK + q * 8;
          bh[i] = *(const short8*)&smem[cur + 4096 + rb];
          bl[i] = *(const short8*)&smem[cur + 8192 + rb];
        }
#pragma unroll
        for (int mi = 0; mi < 2; ++mi)
#pragma unroll
          for (int ni = 0; ni < 2; ++ni) {
            acc[mi][ni] = __builtin_amdgcn_mfma_f32_16x16x32_bf16(ah[mi], bh[ni], acc[mi][ni], 0, 0, 0);
            acc[mi][ni] = __builtin_amdgcn_mfma_f32_16x16x32_bf16(ah[mi], bl[ni], acc[mi][ni], 0, 0, 0);
            acc[mi][ni] = __builtin_amdgcn_mfma_f32_16x16x32_bf16(al[mi], bh[ni], acc[mi][ni], 0, 0, 0);
          }
        __syncthreads();
      }
#pragma unroll
      for (int mi = 0; mi < 2; ++mi)
#pragma unroll
        for (int ni = 0; ni < 2; ++ni) {
          const int n = n0 + wn * 32 + ni * 16 + c16;
          const int mb = m0 + wm * 32 + mi * 16 + q * 4;
          const float bv = bdec[n];
#pragma unroll
          for (int r = 0; r < 4; ++r) {
            const int m = mb + r;
            const size_t idx = (size_t)m * 4096 + n;
            const float cv = canvas[idx] + acc[mi][ni][r] + bv;
            canvas[idx] = cv;
            ehi[(size_t)m * KENC + n] = f2b(x[idx] - sigm(cv));
          }
        }
    }
    if (s + 1 < STEPS) gridbar(bar, ++barid);
  }
}

// ---------------------------------------------------------------------------
extern "C" void kernel_launch(void* const* d_in, const int* in_sizes, int n_in,
                              void* d_out, int out_size, void* d_ws, size_t ws_size,
                              hipStream_t stream) {
  const float* x     = (const float*)d_in[0];
  const float* ek    = (const float*)d_in[1];   // [9728,1024]
  const float* er    = (const float*)d_in[2];   // [256,1024]
  const float* ebias = (const float*)d_in[3];
  const float* dk    = (const float*)d_in[4];   // [256,1024]
  const float* dr    = (const float*)d_in[5];   // [256,1024]
  const float* dbias = (const float*)d_in[6];
  const float* Wenc  = (const float*)d_in[7];   // [256,10]
  const float* benc  = (const float*)d_in[8];
  const float* Wdec  = (const float*)d_in[9];   // [256,4096]
  const float* bdec  = (const float*)d_in[10];

  float* canvas = (float*)d_out;                // [512, 4096] — persistent canvas

  char* p = (char*)d_ws;
  float* c_enc  = (float*)p;        p += (size_t)BSZ * UNITS * 4;
  float* c_dec  = (float*)p;        p += (size_t)BSZ * UNITS * 4;
  float* zep    = (float*)p;        p += (size_t)ESPLIT * BSZ * GATES * 4;
  float* zdp    = (float*)p;        p += (size_t)DSPLIT * BSZ * GATES * 4;
  ushort_t* ehi = (ushort_t*)p;     p += (size_t)BSZ * KENC * 2;
  ushort_t* dhi = (ushort_t*)p;     p += (size_t)BSZ * 512 * 2;
  ushort_t* dlo = (ushort_t*)p;     p += (size_t)BSZ * 512 * 2;
  ushort_t* Wet_hi = (ushort_t*)p;  p += (size_t)GATES * KENC * 2;      // [1024][4608]
  ushort_t* Wdt_hi = (ushort_t*)p;  p += (size_t)GATES * 512 * 2;       // [1024][512]
  ushort_t* Wdt_lo = (ushort_t*)p;  p += (size_t)GATES * 512 * 2;
  ushort_t* Wct_hi = (ushort_t*)p;  p += (size_t)4096 * UNITS * 2;      // [4096][256]
  ushort_t* Wct_lo = (ushort_t*)p;  p += (size_t)4096 * UNITS * 2;
  unsigned* bar = (unsigned*)p;     p += (size_t)(NBLK * FLAG_STRIDE + 16) * 4;

  // ---- weight prep (once per launch) ----
  k_prep_pix<<<dim3(64, 16), 256, 0, stream>>>(ek, Wet_hi);
  k_prep_multi<<<dim3(4, 16, 8), 256, 0, stream>>>(ek, er, dk, dr, Wdec,
                                                   Wet_hi, Wdt_hi, Wdt_lo,
                                                   Wct_hi, Wct_lo, bar);

  // ---- persistent 10-step kernel (cooperative; fallback to plain launch) ----
  void* args[] = {(void*)&x, (void*)&ebias, (void*)&dbias, (void*)&Wenc,
                  (void*)&benc, (void*)&bdec, (void*)&canvas, (void*)&c_enc,
                  (void*)&c_dec, (void*)&zep, (void*)&zdp, (void*)&ehi,
                  (void*)&dhi, (void*)&dlo, (void*)&Wet_hi, (void*)&Wdt_hi,
                  (void*)&Wdt_lo, (void*)&Wct_hi, (void*)&Wct_lo, (void*)&bar};
  if (hipLaunchCooperativeKernel((void*)k_persist, dim3(NBLK), dim3(512),
                                 args, 0, stream) != hipSuccess) {
    k_persist<<<dim3(NBLK), dim3(512), 0, stream>>>(
        x, ebias, dbias, Wenc, benc, bdec, canvas, c_enc, c_dec, zep, zdp,
        ehi, dhi, dlo, Wet_hi, Wdt_hi, Wdt_lo, Wct_hi, Wct_lo, bar);
  }
}

// Round 3
// 1151.404 us; speedup vs baseline: 2.2662x; 1.5994x over previous
//
#include <hip/hip_runtime.h>

typedef unsigned short ushort_t;
typedef __attribute__((ext_vector_type(8))) short short8;
typedef __attribute__((ext_vector_type(4))) float floatx4;
typedef __attribute__((ext_vector_type(4))) unsigned int uintx4;

#define BSZ   512
#define UNITS 256
#define IMG   64
#define STEPS 10
#define GATES 1024
// folded ext layout per batch row: [x_hat 4096 | h_dec 256 | h_enc 256]
#define KENC  4608
#define ESPLIT 8    // enc: 144 kt = 8 chunks of 18
#define DSPLIT 4    // dec: 16 kt = 4 chunks of 4
#define NBLK  256   // persistent grid: one block per CU
#define TM 128
#define TN 128
#define BK 32
#define FLAG_STRIDE 32                       // 128 B per block flag slot

__device__ inline float b2f(ushort_t u) {
  union { float f; unsigned int i; } v; v.i = ((unsigned int)u) << 16; return v.f;
}
__device__ inline ushort_t f2b(float f) {
  unsigned int u = __float_as_uint(f);
  u += 0x7fffu + ((u >> 16) & 1u);          // round-to-nearest-even
  return (ushort_t)(u >> 16);
}
__device__ inline float sigm(float x) { return 1.f / (1.f + __expf(-x)); }

#define GLL(g, l) __builtin_amdgcn_global_load_lds(                      \
    (const __attribute__((address_space(1))) void*)(g),                  \
    (__attribute__((address_space(3))) void*)(l), 16, 0, 0)

// Coherent (L2-bypassing) scalar ops: relaxed agent atomics -> sc0 sc1, no
// wbl2/inv cache maintenance.
#define CLOADF(p)    __hip_atomic_load((p), __ATOMIC_RELAXED, __HIP_MEMORY_SCOPE_AGENT)
#define CSTOREF(p,v) __hip_atomic_store((p), (v), __ATOMIC_RELAXED, __HIP_MEMORY_SCOPE_AGENT)
#define CSTOREU(p,v) __hip_atomic_store((p), (ushort_t)(v), __ATOMIC_RELAXED, __HIP_MEMORY_SCOPE_AGENT)

// 16B coherent global load (result NOT ready until s_waitcnt vmcnt).
__device__ inline uintx4 cload16(const ushort_t* p) {
  uintx4 r;
  asm volatile("global_load_dwordx4 %0, %1, off sc0 sc1" : "=v"(r) : "v"(p));
  return r;
}
__device__ inline void waitvm0() {
  asm volatile("s_waitcnt vmcnt(0)" ::: "memory");
}
__device__ inline unsigned ldsaddr(const ushort_t* p) {
  return (unsigned)(unsigned long long)(const __attribute__((address_space(3))) void*)p;
}
__device__ inline void dsw16(unsigned off, uintx4 v) {
  asm volatile("ds_write_b128 %0, %1" :: "v"(off), "v"(v));
}

// ---------------------------------------------------------------------------
// Grid barrier, zero cache-maintenance: per-block arrival flags (relaxed
// agent atomics = sc1, no wbl2/inv) + leader block 0 aggregation + relaxed
// generation broadcast. The entry __syncthreads drains each wave's vmcnt so
// all sc1 data stores are globally visible before the flag is raised.
// Cross-block data is ONLY accessed via sc1 ops, so no fences are needed.
// ---------------------------------------------------------------------------
__device__ inline void gridbar(unsigned* bar, unsigned id) {
  __syncthreads();
  const int b = blockIdx.x, t = threadIdx.x;
  unsigned* gen = bar + NBLK * FLAG_STRIDE;
  if (b == 0) {
    if (t > 0 && t < NBLK) {
      while (__hip_atomic_load(bar + t * FLAG_STRIDE, __ATOMIC_RELAXED,
                               __HIP_MEMORY_SCOPE_AGENT) < id)
        __builtin_amdgcn_s_sleep(1);
    }
    __syncthreads();
    if (t == 0)
      __hip_atomic_store(gen, id, __ATOMIC_RELAXED, __HIP_MEMORY_SCOPE_AGENT);
  } else if (t == 0) {
    __hip_atomic_store(bar + b * FLAG_STRIDE, id, __ATOMIC_RELAXED,
                       __HIP_MEMORY_SCOPE_AGENT);
    while (__hip_atomic_load(gen, __ATOMIC_RELAXED,
                             __HIP_MEMORY_SCOPE_AGENT) < id)
      __builtin_amdgcn_s_sleep(1);
  }
  __syncthreads();
}

// ---------------------------------------------------------------------------
// Fold patch weights into per-pixel weights + transpose (hi only).
// ---------------------------------------------------------------------------
__global__ __launch_bounds__(256) void k_prep_pix(const float* __restrict__ ek,
                                                  ushort_t* __restrict__ ohi) {
  __shared__ float T[64][68];
  int t = threadIdx.x;
  int pix0 = blockIdx.x * 64, n0 = blockIdx.y * 64;
  int r = t >> 2, seg = t & 3;
  int pix = pix0 + r;
  int ri = pix >> 6, ci = pix & 63;
  float4 acc4[4];
#pragma unroll
  for (int j = 0; j < 4; ++j) acc4[j] = float4{0.f, 0.f, 0.f, 0.f};
#pragma unroll
  for (int di = 0; di < 3; ++di) {
    int ii = ri - di;
    if (ii < 0 || (ii & 1)) continue;
    int oi = ii >> 1;  if (oi >= 32) continue;
#pragma unroll
    for (int dj = 0; dj < 3; ++dj) {
      int jj = ci - dj;
      if (jj < 0 || (jj & 1)) continue;
      int oj = jj >> 1;  if (oj >= 32) continue;
      const float* row = ek + (size_t)((oi * 32 + oj) * 9 + di * 3 + dj) * GATES
                         + n0 + seg * 16;
#pragma unroll
      for (int j = 0; j < 4; ++j) {
        float4 v = *(const float4*)(row + j * 4);
        acc4[j].x += v.x; acc4[j].y += v.y; acc4[j].z += v.z; acc4[j].w += v.w;
      }
    }
  }
#pragma unroll
  for (int j = 0; j < 4; ++j) *(float4*)&T[r][seg * 16 + j * 4] = acc4[j];
  __syncthreads();
  ushort_t thi[16];
#pragma unroll
  for (int j = 0; j < 16; ++j) thi[j] = f2b(T[seg * 16 + j][r]);
  size_t off = (size_t)(n0 + r) * KENC + pix0 + seg * 16;
  *(uint4*)(ohi + off)     = *(const uint4*)&thi[0];
  *(uint4*)(ohi + off + 8) = *(const uint4*)&thi[8];
}

// ---------------------------------------------------------------------------
// Multi-job transpose prep (one dispatch). Also zeroes the grid-barrier words.
// ---------------------------------------------------------------------------
__global__ __launch_bounds__(256) void k_prep_multi(
    const float* __restrict__ ek, const float* __restrict__ er,
    const float* __restrict__ dk, const float* __restrict__ dr,
    const float* __restrict__ Wdec,
    ushort_t* __restrict__ Wet_hi,
    ushort_t* __restrict__ Wdt_hi, ushort_t* __restrict__ Wdt_lo,
    ushort_t* __restrict__ Wct_hi, ushort_t* __restrict__ Wct_lo,
    unsigned* __restrict__ bar) {
  __shared__ float T[64][68];
  int t = threadIdx.x;
  int z = blockIdx.z;
  int k0 = blockIdx.x * 64, n0 = blockIdx.y * 64;
  int r = t >> 2, seg = t & 3;
  if (z == 0) {
    int fid = (blockIdx.y * 4 + blockIdx.x) * 256 + t;
    if (fid <= NBLK * FLAG_STRIDE) bar[fid] = 0u;   // flags + gen
  }

  const float *s0, *s1 = nullptr;
  ushort_t *ohi, *olo = nullptr;
  int src_ld, out_ld, koff;
  if (z == 0) { s0 = ek + (size_t)9216 * GATES; s1 = ek + (size_t)9472 * GATES;
                src_ld = GATES; ohi = Wet_hi; out_ld = KENC; koff = 4096; }
  else if (z == 1) { s0 = er; src_ld = GATES; ohi = Wet_hi; out_ld = KENC; koff = 4352; }
  else if (z == 2) { s0 = dk; src_ld = GATES; ohi = Wdt_hi; olo = Wdt_lo; out_ld = 512; koff = 0; }
  else if (z == 3) { s0 = dr; src_ld = GATES; ohi = Wdt_hi; olo = Wdt_lo; out_ld = 512; koff = 256; }
  else { s0 = Wdec; src_ld = 4096; ohi = Wct_hi; olo = Wct_lo; out_ld = 256; koff = 0;
         n0 += (z - 4) * 1024; }

  const float* src = s0 + (size_t)(k0 + r) * src_ld + n0 + seg * 16;
  const float* src2 = s1 ? (s1 + (size_t)(k0 + r) * src_ld + n0 + seg * 16) : nullptr;
#pragma unroll
  for (int j = 0; j < 4; ++j) {
    float4 v = *(const float4*)(src + j * 4);
    if (src2) {
      float4 w = *(const float4*)(src2 + j * 4);
      v.x += w.x; v.y += w.y; v.z += w.z; v.w += w.w;
    }
    *(float4*)&T[r][seg * 16 + j * 4] = v;
  }
  __syncthreads();
  ushort_t thi[16], tlo[16];
#pragma unroll
  for (int j = 0; j < 16; ++j) {
    float v = T[seg * 16 + j][r];
    ushort_t h = f2b(v);
    thi[j] = h;
    tlo[j] = f2b(v - b2f(h));
  }
  size_t off = (size_t)(n0 + r) * out_ld + koff + k0 + seg * 16;
  *(uint4*)(ohi + off)     = *(const uint4*)&thi[0];
  *(uint4*)(ohi + off + 8) = *(const uint4*)&thi[8];
  if (olo) {
    *(uint4*)(olo + off)     = *(const uint4*)&tlo[0];
    *(uint4*)(olo + off + 8) = *(const uint4*)&tlo[8];
  }
}

// ---------------------------------------------------------------------------
// Persistent kernel: all 10 steps, 5 phases/step, grid barriers in between.
// 256 blocks x 512 threads (8 waves) = 1 block/CU. LDS union = 48 KiB.
// Activations cross blocks only via sc1 (LLC) path; weights stay L2-cached.
// LDS tiles use seg^=(row>>1)&3 source swizzle + q^=(c16>>1)&3 read swizzle
// (8-way -> 2-way bank conflicts on ds_read_b128).
// ---------------------------------------------------------------------------
__global__ __launch_bounds__(512, 2) void k_persist(
    const float* __restrict__ x,
    const float* __restrict__ ebias, const float* __restrict__ dbias,
    const float* __restrict__ Wenc, const float* __restrict__ benc,
    const float* __restrict__ bdec,
    float* __restrict__ canvas, float* __restrict__ c_enc, float* __restrict__ c_dec,
    float* __restrict__ zep, float* __restrict__ zdp,
    ushort_t* __restrict__ ehi, ushort_t* __restrict__ dhi, ushort_t* __restrict__ dlo,
    const ushort_t* __restrict__ Wet_hi,
    const ushort_t* __restrict__ Wdt_hi, const ushort_t* __restrict__ Wdt_lo,
    const ushort_t* __restrict__ Wct_hi, const ushort_t* __restrict__ Wct_lo,
    unsigned* bar) {
  __shared__ __align__(16) ushort_t smem[24576];   // 48 KiB union for all phases
  const int b = blockIdx.x, t = threadIdx.x;
  const int lane = t & 63, w = t >> 6;
  const int q = lane >> 4, c16 = lane & 15;
  const int sw = (c16 >> 1) & 3;                   // read-side swizzle
  const int qs = (q ^ sw) * 8;                     // swizzled k-seg (ushort)
  const int half = t >> 8, u8 = t & 255;
  const int rrow = b * 2 + half;                   // 2 batch rows per block
  unsigned barid = 0;

  // ---------------- preamble: zero state + step-0 x_hat (sigmoid(0)=0.5) ----
  {
    float4* cv4 = (float4*)canvas;
    float4 z4 = float4{0.f, 0.f, 0.f, 0.f};
#pragma unroll
    for (int i = 0; i < 4; ++i) cv4[b * 2048 + i * 512 + t] = z4;
    c_enc[b * 512 + t] = 0.f;
    c_dec[b * 512 + t] = 0.f;
    CSTOREU(ehi + (size_t)rrow * KENC + 4096 + u8, 0);
    CSTOREU(ehi + (size_t)rrow * KENC + 4352 + u8, 0);
    CSTOREU(dhi + (size_t)rrow * 512 + u8, 0);
    CSTOREU(dhi + (size_t)rrow * 512 + 256 + u8, 0);
    CSTOREU(dlo + (size_t)rrow * 512 + u8, 0);
    CSTOREU(dlo + (size_t)rrow * 512 + 256 + u8, 0);
    for (int pix = u8; pix < 4096; pix += 256)
      CSTOREU(ehi + (size_t)rrow * KENC + pix,
              f2b(x[(size_t)rrow * 4096 + pix] - 0.5f));
  }
  gridbar(bar, ++barid);

  for (int s = 0; s < STEPS; ++s) {
    // ============ phase E: enc GEMM, pure bf16, 128x128 tile, split-K 8 =====
    {
      const int z = b >> 5, by = (b >> 3) & 3, bx = b & 7;
      const int m0 = by * TM, n0 = bx * TN, kstart = z * 18 * BK;
      const int wm = w >> 1, wn = w & 1;           // 4x2 waves -> 32m x 64n
      const int srow = t >> 2;                     // staging row 0..127
      const int sseg = ((t & 3) ^ ((t >> 3) & 3)); // pre-swizzled source seg
      const ushort_t* pAh = ehi + (size_t)(m0 + srow) * KENC + kstart + sseg * 8;
      const ushort_t* pBh = Wet_hi + (size_t)(n0 + srow) * KENC + kstart + sseg * 8;

      floatx4 acc[2][4];
#pragma unroll
      for (int i = 0; i < 2; ++i)
#pragma unroll
        for (int j = 0; j < 4; ++j) acc[i][j] = floatx4{0.f, 0.f, 0.f, 0.f};

      // prologue: stage buffer 0
      {
        uintx4 va = cload16(pAh);
        GLL(pBh, &smem[4096 + t * 8]);
        pAh += BK; pBh += BK;
        waitvm0();
        dsw16(ldsaddr(&smem[t * 8]), va);
      }
      __syncthreads();
      for (int kt = 0; kt < 18; ++kt) {
        const int cur = (kt & 1) * 8192, nxt = 8192 - cur;
        uintx4 va;
        if (kt + 1 < 18) {
          va = cload16(pAh);
          GLL(pBh, &smem[nxt + 4096 + t * 8]);
          pAh += BK; pBh += BK;
        }
        short8 ah[2], bh[4];
#pragma unroll
        for (int i = 0; i < 2; ++i)
          ah[i] = *(const short8*)&smem[cur + (wm * 32 + i * 16 + c16) * BK + qs];
#pragma unroll
        for (int j = 0; j < 4; ++j)
          bh[j] = *(const short8*)&smem[cur + 4096 + (wn * 64 + j * 16 + c16) * BK + qs];
#pragma unroll
        for (int mi = 0; mi < 2; ++mi)
#pragma unroll
          for (int ni = 0; ni < 4; ++ni)
            acc[mi][ni] = __builtin_amdgcn_mfma_f32_16x16x32_bf16(ah[mi], bh[ni], acc[mi][ni], 0, 0, 0);
        if (kt + 1 < 18) {
          waitvm0();
          dsw16(ldsaddr(&smem[nxt + t * 8]), va);
        }
        __syncthreads();
      }
#pragma unroll
      for (int mi = 0; mi < 2; ++mi)
#pragma unroll
        for (int ni = 0; ni < 4; ++ni) {
          const int n = n0 + wn * 64 + ni * 16 + c16;
          const int mb = m0 + wm * 32 + mi * 16 + q * 4;
#pragma unroll
          for (int r = 0; r < 4; ++r)
            CSTOREF(zep + ((size_t)(mb + r) * ESPLIT + z) * GATES + n, acc[mi][ni][r]);
        }
    }
    gridbar(bar, ++barid);

    // ============ phase E2: enc LSTM + attention softmax + glimpse ==========
    {
      float* shf = (float*)smem;          // [0,512): h (2 rows); [512,532): logits
      const float* rb = zep + (size_t)rrow * (ESPLIT * GATES) + u8;
      float v[32];
#pragma unroll
      for (int sp = 0; sp < 8; ++sp)
#pragma unroll
        for (int g = 0; g < 4; ++g)
          v[sp * 4 + g] = CLOADF(rb + sp * GATES + g * 256);
      float zi = ebias[u8], zf = ebias[u8 + 256];
      float zg = ebias[u8 + 512], zo = ebias[u8 + 768];
#pragma unroll
      for (int sp = 0; sp < 8; ++sp) {
        zi += v[sp * 4]; zf += v[sp * 4 + 1]; zg += v[sp * 4 + 2]; zo += v[sp * 4 + 3];
      }
      float c = c_enc[rrow * UNITS + u8];
      float cn = sigm(zf) * c + sigm(zi) * tanhf(zg);
      float h = sigm(zo) * tanhf(cn);
      c_enc[rrow * UNITS + u8] = cn;
      CSTOREU(ehi + (size_t)rrow * KENC + 4352 + u8, f2b(h));
      shf[half * 256 + u8] = h;
      __syncthreads();
      if (u8 < 64) {    // waves 0 and 4: full-wave shuffle reduce per row
        float acc[10];
#pragma unroll
        for (int j = 0; j < 10; ++j) acc[j] = 0.f;
        for (int qq = 0; qq < 4; ++qq) {
          float hv = shf[half * 256 + u8 + qq * 64];
          const float* wr = Wenc + (u8 + qq * 64) * 10;
#pragma unroll
          for (int j = 0; j < 10; ++j) acc[j] += hv * wr[j];
        }
        for (int off = 32; off > 0; off >>= 1)
#pragma unroll
          for (int j = 0; j < 10; ++j) acc[j] += __shfl_down(acc[j], off);
        if (u8 == 0)
          for (int j = 0; j < 10; ++j) shf[512 + half * 10 + j] = acc[j] + benc[j];
      }
      __syncthreads();
      float mx = shf[512 + half * 10];
      for (int j = 1; j < 10; ++j) mx = fmaxf(mx, shf[512 + half * 10 + j]);
      float e[10], se = 0.f;
      for (int j = 0; j < 10; ++j) { e[j] = __expf(shf[512 + half * 10 + j] - mx); se += e[j]; }
      float inv = 1.f / se;
      const float* wr = Wenc + u8 * 10;
      float zzv = 0.f;
      for (int j = 0; j < 10; ++j) zzv += e[j] * inv * wr[j];
      ushort_t zh = f2b(zzv);
      CSTOREU(dhi + (size_t)rrow * 512 + u8, zh);
      CSTOREU(dlo + (size_t)rrow * 512 + u8, f2b(zzv - b2f(zh)));
    }
    gridbar(bar, ++barid);

    // ============ phase D: dec GEMM, 3-product, 128x64 tile, split-K 4 ======
    {
      const int z = b >> 6, rem = b & 63, by = rem >> 4, bx = rem & 15;
      const int m0 = by * TM, n0 = bx * 64, kstart = z * 4 * BK;
      const int wm = w >> 1, wn = w & 1;           // 4x2 waves -> 32m x 32n
      const int ta = t & 255;
      const int sseg = ((t & 3) ^ ((t >> 3) & 3));
      const int bseg = ((ta & 3) ^ ((ta >> 3) & 3));
      const ushort_t* pAh = dhi + (size_t)(m0 + (t >> 2)) * 512 + kstart + sseg * 8;
      const ushort_t* pAl = dlo + (size_t)(m0 + (t >> 2)) * 512 + kstart + sseg * 8;
      const ushort_t* pB = ((t < 256) ? Wdt_hi : Wdt_lo)
                           + (size_t)(n0 + (ta >> 2)) * 512 + kstart + bseg * 8;
      const int dB = ((t < 256) ? 8192 : 10240) + ta * 8;

      floatx4 acc[2][2];
#pragma unroll
      for (int i = 0; i < 2; ++i)
#pragma unroll
        for (int j = 0; j < 2; ++j) acc[i][j] = floatx4{0.f, 0.f, 0.f, 0.f};

      {
        uintx4 vah = cload16(pAh);
        uintx4 val = cload16(pAl);
        GLL(pB, &smem[dB]);
        pAh += BK; pAl += BK; pB += BK;
        waitvm0();
        dsw16(ldsaddr(&smem[t * 8]), vah);
        dsw16(ldsaddr(&smem[4096 + t * 8]), val);
      }
      __syncthreads();
      for (int kt = 0; kt < 4; ++kt) {
        const int cur = (kt & 1) * 12288, nxt = 12288 - cur;
        uintx4 vah, val;
        if (kt + 1 < 4) {
          vah = cload16(pAh);
          val = cload16(pAl);
          GLL(pB, &smem[nxt + dB]);
          pAh += BK; pAl += BK; pB += BK;
        }
        short8 ah[2], al[2], bh[2], bl[2];
#pragma unroll
        for (int i = 0; i < 2; ++i) {
          const int ra = (wm * 32 + i * 16 + c16) * BK + qs;
          ah[i] = *(const short8*)&smem[cur + ra];
          al[i] = *(const short8*)&smem[cur + 4096 + ra];
          const int rb2 = (wn * 32 + i * 16 + c16) * BK + qs;
          bh[i] = *(const short8*)&smem[cur + 8192 + rb2];
          bl[i] = *(const short8*)&smem[cur + 10240 + rb2];
        }
#pragma unroll
        for (int mi = 0; mi < 2; ++mi)
#pragma unroll
          for (int ni = 0; ni < 2; ++ni) {
            acc[mi][ni] = __builtin_amdgcn_mfma_f32_16x16x32_bf16(ah[mi], bh[ni], acc[mi][ni], 0, 0, 0);
            acc[mi][ni] = __builtin_amdgcn_mfma_f32_16x16x32_bf16(ah[mi], bl[ni], acc[mi][ni], 0, 0, 0);
            acc[mi][ni] = __builtin_amdgcn_mfma_f32_16x16x32_bf16(al[mi], bh[ni], acc[mi][ni], 0, 0, 0);
          }
        if (kt + 1 < 4) {
          waitvm0();
          dsw16(ldsaddr(&smem[nxt + t * 8]), vah);
          dsw16(ldsaddr(&smem[nxt + 4096 + t * 8]), val);
        }
        __syncthreads();
      }
#pragma unroll
      for (int mi = 0; mi < 2; ++mi)
#pragma unroll
        for (int ni = 0; ni < 2; ++ni) {
          const int n = n0 + wn * 32 + ni * 16 + c16;
          const int mb = m0 + wm * 32 + mi * 16 + q * 4;
#pragma unroll
          for (int r = 0; r < 4; ++r)
            CSTOREF(zdp + ((size_t)(mb + r) * DSPLIT + z) * GATES + n, acc[mi][ni][r]);
        }
    }
    gridbar(bar, ++barid);

    // ============ phase D2: dec LSTM ========================================
    {
      const float* rb = zdp + (size_t)rrow * (DSPLIT * GATES) + u8;
      float v[16];
#pragma unroll
      for (int sp = 0; sp < 4; ++sp)
#pragma unroll
        for (int g = 0; g < 4; ++g)
          v[sp * 4 + g] = CLOADF(rb + sp * GATES + g * 256);
      float zi = dbias[u8], zf = dbias[u8 + 256];
      float zg = dbias[u8 + 512], zo = dbias[u8 + 768];
#pragma unroll
      for (int sp = 0; sp < 4; ++sp) {
        zi += v[sp * 4]; zf += v[sp * 4 + 1]; zg += v[sp * 4 + 2]; zo += v[sp * 4 + 3];
      }
      float c = c_dec[rrow * UNITS + u8];
      float cn = sigm(zf) * c + sigm(zi) * tanhf(zg);
      float h = sigm(zo) * tanhf(cn);
      c_dec[rrow * UNITS + u8] = cn;
      ushort_t hh = f2b(h);
      CSTOREU(dhi + (size_t)rrow * 512 + 256 + u8, hh);
      CSTOREU(dlo + (size_t)rrow * 512 + 256 + u8, f2b(h - b2f(hh)));
      CSTOREU(ehi + (size_t)rrow * KENC + 4096 + u8, hh);
    }
    gridbar(bar, ++barid);

    // ============ phase C: canvas GEMM + fused x_hat, 64x128 tiles ==========
    {
      const int by = b >> 5, bx = b & 31;          // 8 m-tiles x 32 n-tiles
      const int m0 = by * 64, n0 = bx * TN;
      const int wm = w >> 2, wn = w & 3;           // 2x4 waves -> 32m x 32n
      const int ia = t & 255;
      const int aseg = ((ia & 3) ^ ((ia >> 3) & 3));
      const int bseg = ((t & 3) ^ ((t >> 3) & 3));
      const ushort_t* pA = ((t < 256) ? (dhi + 256) : (dlo + 256))
                           + (size_t)(m0 + (ia >> 2)) * 512 + aseg * 8;
      const ushort_t* pBh = Wct_hi + (size_t)(n0 + (t >> 2)) * 256 + bseg * 8;
      const ushort_t* pBl = Wct_lo + (size_t)(n0 + (t >> 2)) * 256 + bseg * 8;
      const int dA = ((t < 256) ? 0 : 2048) + ia * 8;

      floatx4 acc[2][2];
#pragma unroll
      for (int i = 0; i < 2; ++i)
#pragma unroll
        for (int j = 0; j < 2; ++j) acc[i][j] = floatx4{0.f, 0.f, 0.f, 0.f};

      {
        uintx4 va = cload16(pA);
        GLL(pBh, &smem[4096 + t * 8]);
        GLL(pBl, &smem[8192 + t * 8]);
        pA += BK; pBh += BK; pBl += BK;
        waitvm0();
        dsw16(ldsaddr(&smem[dA]), va);
      }
      __syncthreads();
      for (int kt = 0; kt < 8; ++kt) {
        const int cur = (kt & 1) * 12288, nxt = 12288 - cur;
        uintx4 va;
        if (kt + 1 < 8) {
          va = cload16(pA);
          GLL(pBh, &smem[nxt + 4096 + t * 8]);
          GLL(pBl, &smem[nxt + 8192 + t * 8]);
          pA += BK; pBh += BK; pBl += BK;
        }
        short8 ah[2], al[2], bh[2], bl[2];
#pragma unroll
        for (int i = 0; i < 2; ++i) {
          const int ra = (wm * 32 + i * 16 + c16) * BK + qs;
          ah[i] = *(const short8*)&smem[cur + ra];
          al[i] = *(const short8*)&smem[cur + 2048 + ra];
          const int rb2 = (wn * 32 + i * 16 + c16) * BK + qs;
          bh[i] = *(const short8*)&smem[cur + 4096 + rb2];
          bl[i] = *(const short8*)&smem[cur + 8192 + rb2];
        }
#pragma unroll
        for (int mi = 0; mi < 2; ++mi)
#pragma unroll
          for (int ni = 0; ni < 2; ++ni) {
            acc[mi][ni] = __builtin_amdgcn_mfma_f32_16x16x32_bf16(ah[mi], bh[ni], acc[mi][ni], 0, 0, 0);
            acc[mi][ni] = __builtin_amdgcn_mfma_f32_16x16x32_bf16(ah[mi], bl[ni], acc[mi][ni], 0, 0, 0);
            acc[mi][ni] = __builtin_amdgcn_mfma_f32_16x16x32_bf16(al[mi], bh[ni], acc[mi][ni], 0, 0, 0);
          }
        if (kt + 1 < 8) {
          waitvm0();
          dsw16(ldsaddr(&smem[nxt + dA]), va);
        }
        __syncthreads();
      }
#pragma unroll
      for (int mi = 0; mi < 2; ++mi)
#pragma unroll
        for (int ni = 0; ni < 2; ++ni) {
          const int n = n0 + wn * 32 + ni * 16 + c16;
          const int mb = m0 + wm * 32 + mi * 16 + q * 4;
          const float bv = bdec[n];
#pragma unroll
          for (int r = 0; r < 4; ++r) {
            const int m = mb + r;
            const size_t idx = (size_t)m * 4096 + n;
            const float cv = canvas[idx] + acc[mi][ni][r] + bv;
            canvas[idx] = cv;
            CSTOREU(ehi + (size_t)m * KENC + n, f2b(x[idx] - sigm(cv)));
          }
        }
    }
    if (s + 1 < STEPS) gridbar(bar, ++barid);
  }
}

// ---------------------------------------------------------------------------
extern "C" void kernel_launch(void* const* d_in, const int* in_sizes, int n_in,
                              void* d_out, int out_size, void* d_ws, size_t ws_size,
                              hipStream_t stream) {
  const float* x     = (const float*)d_in[0];
  const float* ek    = (const float*)d_in[1];   // [9728,1024]
  const float* er    = (const float*)d_in[2];   // [256,1024]
  const float* ebias = (const float*)d_in[3];
  const float* dk    = (const float*)d_in[4];   // [256,1024]
  const float* dr    = (const float*)d_in[5];   // [256,1024]
  const float* dbias = (const float*)d_in[6];
  const float* Wenc  = (const float*)d_in[7];   // [256,10]
  const float* benc  = (const float*)d_in[8];
  const float* Wdec  = (const float*)d_in[9];   // [256,4096]
  const float* bdec  = (const float*)d_in[10];

  float* canvas = (float*)d_out;                // [512, 4096] — persistent canvas

  char* p = (char*)d_ws;
  float* c_enc  = (float*)p;        p += (size_t)BSZ * UNITS * 4;
  float* c_dec  = (float*)p;        p += (size_t)BSZ * UNITS * 4;
  float* zep    = (float*)p;        p += (size_t)ESPLIT * BSZ * GATES * 4;
  float* zdp    = (float*)p;        p += (size_t)DSPLIT * BSZ * GATES * 4;
  ushort_t* ehi = (ushort_t*)p;     p += (size_t)BSZ * KENC * 2;
  ushort_t* dhi = (ushort_t*)p;     p += (size_t)BSZ * 512 * 2;
  ushort_t* dlo = (ushort_t*)p;     p += (size_t)BSZ * 512 * 2;
  ushort_t* Wet_hi = (ushort_t*)p;  p += (size_t)GATES * KENC * 2;      // [1024][4608]
  ushort_t* Wdt_hi = (ushort_t*)p;  p += (size_t)GATES * 512 * 2;       // [1024][512]
  ushort_t* Wdt_lo = (ushort_t*)p;  p += (size_t)GATES * 512 * 2;
  ushort_t* Wct_hi = (ushort_t*)p;  p += (size_t)4096 * UNITS * 2;      // [4096][256]
  ushort_t* Wct_lo = (ushort_t*)p;  p += (size_t)4096 * UNITS * 2;
  unsigned* bar = (unsigned*)p;     p += (size_t)(NBLK * FLAG_STRIDE + 16) * 4;

  // ---- weight prep (once per launch) ----
  k_prep_pix<<<dim3(64, 16), 256, 0, stream>>>(ek, Wet_hi);
  k_prep_multi<<<dim3(4, 16, 8), 256, 0, stream>>>(ek, er, dk, dr, Wdec,
                                                   Wet_hi, Wdt_hi, Wdt_lo,
                                                   Wct_hi, Wct_lo, bar);

  // ---- persistent 10-step kernel (cooperative; fallback to plain launch) ----
  void* args[] = {(void*)&x, (void*)&ebias, (void*)&dbias, (void*)&Wenc,
                  (void*)&benc, (void*)&bdec, (void*)&canvas, (void*)&c_enc,
                  (void*)&c_dec, (void*)&zep, (void*)&zdp, (void*)&ehi,
                  (void*)&dhi, (void*)&dlo, (void*)&Wet_hi, (void*)&Wdt_hi,
                  (void*)&Wdt_lo, (void*)&Wct_hi, (void*)&Wct_lo, (void*)&bar};
  if (hipLaunchCooperativeKernel((void*)k_persist, dim3(NBLK), dim3(512),
                                 args, 0, stream) != hipSuccess) {
    k_persist<<<dim3(NBLK), dim3(512), 0, stream>>>(
        x, ebias, dbias, Wenc, benc, bdec, canvas, c_enc, c_dec, zep, zdp,
        ehi, dhi, dlo, Wet_hi, Wdt_hi, Wdt_lo, Wct_hi, Wct_lo, bar);
  }
}